// Round 5
// baseline (1190.123 us; speedup 1.0000x reference)
//
#include <hip/hip_runtime.h>
#include <math.h>

// Model constants
static constexpr int Bc = 64;
static constexpr int Kc = 1024;
static constexpr int Cc = 512;
static constexpr int Dc = 256;
static constexpr int Hc = 4;
static constexpr int Sc = 1026;       // 2 + K
static constexpr int FFc = 1024;
static constexpr float EPSc = 1e-5f;
static constexpr float SCALEc = 0.125f;   // 1/sqrt(64)
static constexpr float NEG_OUT = -1.0e30f;  // finite stand-in for -inf

typedef __attribute__((ext_vector_type(8))) short short8;
typedef __attribute__((ext_vector_type(8))) unsigned short u16x8;
typedef __attribute__((ext_vector_type(4))) float f32x4;

__device__ __forceinline__ float bf2f(unsigned short u) {
  union { float f; unsigned int i; } c; c.i = ((unsigned int)u) << 16; return c.f;
}
__device__ __forceinline__ unsigned short f2bf(float f) {
  union { float f; unsigned int i; } c; c.f = f;
  unsigned int i = c.i;
  unsigned int r = (i + 0x7fffu + ((i >> 16) & 1u)) >> 16;  // RNE
  return (unsigned short)r;
}
// Packed f32x2 -> bf16x2 (RNE), 1 instruction. Low16 = a, high16 = b.
__device__ __forceinline__ unsigned int cvt_pk_bf16(float a, float b) {
  unsigned int d;
  asm("v_cvt_pk_bf16_f32 %0, %1, %2" : "=v"(d) : "v"(a), "v"(b));
  return d;
}

__device__ __forceinline__ float wave_sum(float v) {
#pragma unroll
  for (int off = 32; off > 0; off >>= 1) v += __shfl_xor(v, off, 64);
  return v;
}
__device__ __forceinline__ float wave_max(float v) {
#pragma unroll
  for (int off = 32; off > 0; off >>= 1) v = fmaxf(v, __shfl_xor(v, off, 64));
  return v;
}

__device__ __forceinline__ void async_ld16(const unsigned short* g, unsigned short* l) {
  __builtin_amdgcn_global_load_lds(
      (const __attribute__((address_space(1))) void*)g,
      (__attribute__((address_space(3))) void*)l, 16, 0, 0);
}

// Fast GELU, tanh-form (err ~1e-3 rel, below bf16 rounding).
__device__ __forceinline__ float gelu_fast(float u) {
  const float z = u * fmaf(u * u, 0.07135481627f, 1.5957691216f);
  return __fdividef(u, 1.0f + __expf(-z));
}

// ---------------------------------------------------------------------------
// bf16 MFMA GEMM, tile 128m x 256n, BK=32, 3-buffer LDS pipeline with
// counted vmcnt (R3-verified protocol, R13: N-tile 128->256).
// Rationale: per-block K-chain latency (~40k cy for 8 iters) dominates and is
// width-independent -> double MFMA per chain (32/iter/wave), halve block
// count. NB=1 for all N=256 GEMMs (Wo/FF2/embed: A staged exactly once).
// LDS: A 3x8KB @[0,12288), B 3x16KB @[12288,36864) ushorts = 72KB ->
// 2 blocks/CU. Epilogue C-tile [128][256] bf16 (32768 ushorts) reuses LDS.
// Stage = 6 DMA/thread (2 A + 4 B); depth-2 prefetch -> vmcnt(6) steady.
// Safety: buffer overwritten at stage(it+2) was read at iter it-1; all waves
// drained ds_reads (lgkmcnt(0)) before barrier it. Epilogue loads can't
// hoist into the counted region past the "memory"-clobbered asm.
// A: [M][Kd] bf16 (CASTA=0) or fp32 (CASTA=1, cast fused, compiler-managed
// 2-buffer loop). W: [N][Kd] bf16. EPI: 1 +extraF[n]; 2 +bf16 residual
// extraB (in-place OK); 3 fast GELU; 4 bias only. Outputs bf16.
// MAP: 1 = candidate row scatter m -> (m>>10)*1026+2+(m&1023).
// ---------------------------------------------------------------------------
template <int EPI, int MAP, int CASTA>
__global__ __launch_bounds__(256) void gemm_mfma(
    const void* __restrict__ Av, const unsigned short* __restrict__ W,
    const float* __restrict__ bias, const void* extra,
    void* Cout, int N, int Kd, int ldc, int MB, int NB) {
  __shared__ unsigned short lds[36864];   // 72 KB
  const int xcd = blockIdx.x & 7;
  const int slot = blockIdx.x >> 3;
  const int nb = slot % NB;
  const int mb = (slot / NB) * 8 + xcd;
  if (mb >= MB) return;
  const int m0 = mb * 128;
  const int n0 = nb * 256;
  const int tid = threadIdx.x;
  const int w = tid >> 6;
  const int lane = tid & 63;

  const unsigned short* A = (const unsigned short*)Av;
  const float* Af = (const float*)Av;

  // A staging: wave w, call c (0/1): rows (w*2+c)*16 + lane>>2, 16B/lane.
  // B staging: wave w, call c (0..3): rows (w*4+c)*16 + lane>>2.
  // Phys chunk = lane&3; global chunk XOR (row>>1)&3 (matches koff read).
  const int rsub = lane >> 2;
  const unsigned short* pA[2];
  const unsigned short* pB[4];
#pragma unroll
  for (int c = 0; c < 2; ++c) {
    const int r = (w * 2 + c) * 16 + rsub;
    const int kc = ((lane & 3) ^ ((r >> 1) & 3)) * 8;
    if (!CASTA) pA[c] = A + (size_t)(m0 + r) * Kd + kc;
  }
#pragma unroll
  for (int c = 0; c < 4; ++c) {
    const int r = (w * 4 + c) * 16 + rsub;
    const int kc = ((lane & 3) ^ ((r >> 1) & 3)) * 8;
    pB[c] = W + (size_t)(n0 + r) * Kd + kc;
  }
  const int lregA[2] = {(w * 2 + 0) * 512, (w * 2 + 1) * 512};
  const int lregB[4] = {(w * 4 + 0) * 512, (w * 4 + 1) * 512,
                        (w * 4 + 2) * 512, (w * 4 + 3) * 512};

  f32x4 zero = {0.f, 0.f, 0.f, 0.f};
  f32x4 acc[4][8];
#pragma unroll
  for (int i = 0; i < 4; ++i)
#pragma unroll
    for (int j = 0; j < 8; ++j) acc[i][j] = zero;

  const int mrow = (w & 1) * 64;      // wave covers [64m x 128n]
  const int ncol = (w >> 1) * 128;
  const int l15 = lane & 15;
  const int quad = lane >> 4;
  const int koff = (quad ^ ((l15 >> 1) & 3)) * 16;  // byte offset of k-chunk

  auto stage = [&](int kk, int b) {
    if (CASTA) {
      // fp32 A -> bf16 LDS: 4 x (float4 load, packed cvt, 8B ds_write).
#pragma unroll
      for (int wi = 0; wi < 4; ++wi) {
        const int g = wi * 256 + tid;     // 0..1023
        const int row = g >> 3;
        const int k4 = g & 7;
        const int phys =
            row * 32 + ((((k4 >> 1) ^ ((row >> 1) & 3))) << 3) + ((k4 & 1) << 2);
        const float4 a4 =
            *(const float4*)(Af + (size_t)(m0 + row) * Kd + kk + k4 * 4);
        uint2 o;
        o.x = cvt_pk_bf16(a4.x, a4.y);
        o.y = cvt_pk_bf16(a4.z, a4.w);
        *(uint2*)(&lds[b * 4096 + phys]) = o;
      }
    } else {
      async_ld16(pA[0] + kk, &lds[b * 4096 + lregA[0]]);
      async_ld16(pA[1] + kk, &lds[b * 4096 + lregA[1]]);
    }
#pragma unroll
    for (int c = 0; c < 4; ++c)
      async_ld16(pB[c] + kk, &lds[12288 + b * 8192 + lregB[c]]);
  };

  auto compute_tile = [&](int cur) {
    const char* AsB = (const char*)&lds[cur * 4096];
    const char* WsB = (const char*)&lds[12288 + cur * 8192];
    short8 af[4], bfr[8];
#pragma unroll
    for (int i = 0; i < 4; ++i)
      af[i] = *(const short8*)(AsB + (size_t)(mrow + i * 16 + l15) * 64 + koff);
#pragma unroll
    for (int j = 0; j < 8; ++j)
      bfr[j] = *(const short8*)(WsB + (size_t)(ncol + j * 16 + l15) * 64 + koff);
    // Swapped operands (R9): lane's 4 acc regs = 4 consecutive output cols.
#pragma unroll
    for (int i = 0; i < 4; ++i)
#pragma unroll
      for (int j = 0; j < 8; ++j)
        acc[i][j] = __builtin_amdgcn_mfma_f32_16x16x32_bf16(bfr[j], af[i],
                                                            acc[i][j], 0, 0, 0);
  };

  const int niter = Kd >> 5;
  if (CASTA) {
    // Compiler-managed 2-buffer loop (stage has VALU ds_writes).
    stage(0, 0);
    for (int it = 0; it < niter; ++it) {
      const int cur = it & 1;
      __syncthreads();
      if (it + 1 < niter) stage((it + 1) << 5, cur ^ 1);
      compute_tile(cur);
    }
  } else {
    // Deep pipeline: 3 buffers, depth-2 prefetch, counted waits.
    stage(0, 0);
    stage(32, 1);                      // 12 DMA/thread in flight
    int cur = 0;
    for (int it = 0; it < niter; ++it) {
      if (it + 1 < niter)
        asm volatile("s_waitcnt vmcnt(6)" ::: "memory");   // tile it landed
      else
        asm volatile("s_waitcnt vmcnt(0)" ::: "memory");
      asm volatile("s_waitcnt lgkmcnt(0)" ::: "memory");   // my ds_reads done
      __builtin_amdgcn_s_barrier();
      if (it + 2 < niter) {
        int b2 = cur + 2; if (b2 >= 3) b2 -= 3;
        stage((it + 2) << 5, b2);      // overwrites buf read at iter it-1
      }
      compute_tile(cur);
      cur = (cur == 2) ? 0 : cur + 1;
    }
  }

  // ---- Epilogue: swizzled b64 C-tile writes + coalesced 16B stores ----
  const float* extraF = (const float*)extra;
  const unsigned short* extraB = (const unsigned short*)extra;
  float4 bj[8];
#pragma unroll
  for (int j = 0; j < 8; ++j) {
    const int n = n0 + ncol + j * 16 + quad * 4;
    float4 t4 = *(const float4*)(bias + n);
    if (EPI == 1) {
      const float4 e4 = *(const float4*)(extraF + n);
      t4.x += e4.x; t4.y += e4.y; t4.z += e4.z; t4.w += e4.w;
    }
    bj[j] = t4;
  }
  __syncthreads();  // all MFMA ds_reads done; LDS becomes C-tile [128][256]
#pragma unroll
  for (int i = 0; i < 4; ++i) {
    const int m = mrow + i * 16 + l15;       // local output row
    const int swz = (m & 7) << 1;            // XOR on granule bits 1..3
#pragma unroll
    for (int j = 0; j < 8; ++j) {
      float v0 = acc[i][j][0] + bj[j].x;
      float v1 = acc[i][j][1] + bj[j].y;
      float v2 = acc[i][j][2] + bj[j].z;
      float v3 = acc[i][j][3] + bj[j].w;
      if (EPI == 3) {
        v0 = gelu_fast(v0); v1 = gelu_fast(v1);
        v2 = gelu_fast(v2); v3 = gelu_fast(v3);
      }
      uint2 pk;
      pk.x = cvt_pk_bf16(v0, v1);
      pk.y = cvt_pk_bf16(v2, v3);
      const int g = ((ncol + j * 16 + quad * 4) >> 2) ^ swz;  // 8B granule
      *(uint2*)(&lds[m * 256 + g * 4]) = pk;
    }
  }
  __syncthreads();
  unsigned short* outb = (unsigned short*)Cout;
#pragma unroll
  for (int p = 0; p < 16; ++p) {
    const int idx = p * 256 + tid;      // 0..4095 chunks of 8 bf16
    const int row = idx >> 5;           // 32 chunks per 256-col row
    const int s = idx & 31;
    const int gsr = (2 * s) ^ ((row & 7) << 1);   // same involution as write
    u16x8 val = *(const u16x8*)(&lds[row * 256 + gsr * 4]);
    const int col = s * 8;
    const int m = m0 + row;
    const size_t orow =
        (MAP == 1) ? ((size_t)(m >> 10) * Sc + 2 + (m & 1023)) : (size_t)m;
    const size_t go = orow * (size_t)ldc + n0 + col;
    if (EPI == 2) {
      u16x8 rv = *(const u16x8*)(extraB + go);
      unsigned int* vp = (unsigned int*)&val;
#pragma unroll
      for (int e = 0; e < 4; ++e) {
        const float a0 = bf2f(val[2 * e]) + bf2f(rv[2 * e]);
        const float a1 = bf2f(val[2 * e + 1]) + bf2f(rv[2 * e + 1]);
        vp[e] = cvt_pk_bf16(a0, a1);
      }
    }
    *(u16x8*)(outb + go) = val;
  }
}

// ---------------------------------------------------------------------------
// Mega weight cast: one dispatch, 10 (src fp32, dst bf16, n4) entries.
// ---------------------------------------------------------------------------
struct CastTab {
  const float* src[10];
  unsigned short* dst[10];
  int n4[10];
};
__global__ __launch_bounds__(256) void cast_multi(CastTab t) {
  const int e = blockIdx.y;
  const int n4 = t.n4[e];
  const float4* s = (const float4*)t.src[e];
  uint2* d = (uint2*)t.dst[e];
  for (int i = blockIdx.x * 256 + threadIdx.x; i < n4; i += gridDim.x * 256) {
    float4 f = s[i];
    uint2 o;
    o.x = cvt_pk_bf16(f.x, f.y);
    o.y = cvt_pk_bf16(f.z, f.w);
    d[i] = o;
  }
}

// Concatenate bq|bk|bv (fp32) per layer into qkvb [L][768].
__global__ __launch_bounds__(256) void bias_concat(const float* bq, const float* bk,
                                                   const float* bv, float* qkvb) {
  const int i = blockIdx.x * 256 + threadIdx.x;
  if (i >= 2 * 768) return;
  const int l = i / 768;
  const int j = i - l * 768;
  float v;
  if (j < 256) v = bq[l * 256 + j];
  else if (j < 512) v = bk[l * 256 + j - 256];
  else v = bv[l * 256 + j - 512];
  qkvb[i] = v;
}

// ---------------------------------------------------------------------------
// Query projection (row s=0) + dustbin token (row s=1) -> bf16 x.
// ---------------------------------------------------------------------------
__global__ __launch_bounds__(256) void embed_qd(
    const float* __restrict__ qin, const float* __restrict__ qp_w,
    const float* __restrict__ qp_b, const float* __restrict__ dustbin,
    const float* __restrict__ type_emb, unsigned short* __restrict__ x) {
  const int b = blockIdx.x;
  const int d = threadIdx.x;
  __shared__ __align__(16) float qs[512];
  qs[d] = qin[b * 512 + d];
  qs[d + 256] = qin[b * 512 + 256 + d];
  __syncthreads();
  float acc = 0.0f;
  const float* wr = qp_w + (size_t)d * 512;
#pragma unroll 4
  for (int c = 0; c < 512; c += 4) {
    float4 w4 = *(const float4*)(wr + c);
    acc = fmaf(qs[c], w4.x, acc);
    acc = fmaf(qs[c + 1], w4.y, acc);
    acc = fmaf(qs[c + 2], w4.z, acc);
    acc = fmaf(qs[c + 3], w4.w, acc);
  }
  const size_t base = (size_t)b * Sc * Dc;
  x[base + d] = f2bf(acc + qp_b[d] + type_emb[d]);
  x[base + Dc + d] = f2bf(dustbin[d] + type_emb[Dc + d]);
}

// ---------------------------------------------------------------------------
// LayerNorm: bf16 in, bf16 out. One wave per row; 4 rows/block.
// ---------------------------------------------------------------------------
__global__ __launch_bounds__(256) void ln_kernel(
    const unsigned short* __restrict__ x, const float* __restrict__ w,
    const float* __restrict__ b, unsigned short* __restrict__ y, int nrows) {
  const int wave = threadIdx.x >> 6;
  const int lane = threadIdx.x & 63;
  const int row = blockIdx.x * 4 + wave;
  if (row >= nrows) return;
  const unsigned short* xr = x + (size_t)row * Dc;
  ushort4 xv = *(const ushort4*)(xr + lane * 4);
  const float v0 = bf2f(xv.x), v1 = bf2f(xv.y), v2 = bf2f(xv.z), v3 = bf2f(xv.w);
  float s = v0 + v1 + v2 + v3;
  float sq = v0 * v0 + v1 * v1 + v2 * v2 + v3 * v3;
  s = wave_sum(s);
  sq = wave_sum(sq);
  const float mean = s * (1.0f / Dc);
  const float var = sq * (1.0f / Dc) - mean * mean;
  const float rs = rsqrtf(var + EPSc);
  float4 wv = *(const float4*)(w + lane * 4);
  float4 bv = *(const float4*)(b + lane * 4);
  uint2 o;
  o.x = cvt_pk_bf16((v0 - mean) * rs * wv.x + bv.x,
                    (v1 - mean) * rs * wv.y + bv.y);
  o.y = cvt_pk_bf16((v2 - mean) * rs * wv.z + bv.z,
                    (v3 - mean) * rs * wv.w + bv.w);
  *(uint2*)(y + (size_t)row * Dc + lane * 4) = o;
}

// ---------------------------------------------------------------------------
// Global-token attention over fused qkv [BS][768] bf16 (q|k|v). Out ao bf16.
// ---------------------------------------------------------------------------
__global__ __launch_bounds__(256) void attn_global(
    const unsigned short* __restrict__ qkv, const unsigned char* __restrict__ mask,
    unsigned short* __restrict__ ao) {
  const int b = blockIdx.x;
  const int h = blockIdx.y;
  const int tid = threadIdx.x;
  const int wv = tid >> 6;
  const int lane = tid & 63;
  __shared__ float q0s[64], q1s[64];
  __shared__ float sc0[Sc], sc1[Sc];
  __shared__ float rbuf[4][2];
  __shared__ float obuf[2][4][64];
  const size_t base = (size_t)b * Sc * 768 + h * 64;
  if (tid < 64) {
    q0s[tid] = bf2f(qkv[base + tid]);
    q1s[tid] = bf2f(qkv[base + 768 + tid]);
  }
  __syncthreads();

  float lm0 = -INFINITY, lm1 = -INFINITY;
  for (int s = tid; s < Sc; s += 256) {
    const unsigned short* kr = qkv + base + 256 + (size_t)s * 768;
    float d0 = 0.0f, d1 = 0.0f;
#pragma unroll
    for (int c = 0; c < 64; c += 8) {
      u16x8 kv = *(const u16x8*)(kr + c);
#pragma unroll
      for (int e = 0; e < 8; ++e) {
        const float kf = bf2f(kv[e]);
        d0 = fmaf(q0s[c + e], kf, d0);
        d1 = fmaf(q1s[c + e], kf, d1);
      }
    }
    const bool pad = (s >= 2) && (mask[b * Kc + (s - 2)] == 0);
    const float s0 = pad ? -INFINITY : d0 * SCALEc;
    const float s1 = pad ? -INFINITY : d1 * SCALEc;
    sc0[s] = s0; sc1[s] = s1;
    lm0 = fmaxf(lm0, s0); lm1 = fmaxf(lm1, s1);
  }
  lm0 = wave_max(lm0);
  lm1 = wave_max(lm1);
  if (lane == 0) { rbuf[wv][0] = lm0; rbuf[wv][1] = lm1; }
  __syncthreads();
  const float m0 = fmaxf(fmaxf(rbuf[0][0], rbuf[1][0]), fmaxf(rbuf[2][0], rbuf[3][0]));
  const float m1 = fmaxf(fmaxf(rbuf[0][1], rbuf[1][1]), fmaxf(rbuf[2][1], rbuf[3][1]));
  float ls0 = 0.0f, ls1 = 0.0f;
  for (int s = tid; s < Sc; s += 256) {
    const float e0 = expf(sc0[s] - m0);
    const float e1 = expf(sc1[s] - m1);
    sc0[s] = e0; sc1[s] = e1;
    ls0 += e0; ls1 += e1;
  }
  ls0 = wave_sum(ls0);
  ls1 = wave_sum(ls1);
  __syncthreads();
  if (lane == 0) { rbuf[wv][0] = ls0; rbuf[wv][1] = ls1; }
  __syncthreads();
  const float t0 = rbuf[0][0] + rbuf[1][0] + rbuf[2][0] + rbuf[3][0];
  const float t1 = rbuf[0][1] + rbuf[1][1] + rbuf[2][1] + rbuf[3][1];
  float o0 = 0.0f, o1 = 0.0f;
  for (int s = wv; s < Sc; s += 4) {
    const float vvv = bf2f(qkv[base + 512 + (size_t)s * 768 + lane]);
    o0 = fmaf(sc0[s], vvv, o0);
    o1 = fmaf(sc1[s], vvv, o1);
  }
  obuf[0][wv][lane] = o0;
  obuf[1][wv][lane] = o1;
  __syncthreads();
  if (wv == 0) {
    const float a0 = obuf[0][0][lane] + obuf[0][1][lane] + obuf[0][2][lane] + obuf[0][3][lane];
    const float a1 = obuf[1][0][lane] + obuf[1][1][lane] + obuf[1][2][lane] + obuf[1][3][lane];
    const size_t ob = ((size_t)b * Sc) * Dc + h * 64;
    ao[ob + lane] = f2bf(a0 / t0);
    ao[ob + Dc + lane] = f2bf(a1 / t1);
  }
}

// ---------------------------------------------------------------------------
// Candidate attention over fused qkv: {global0, global1, self}. Out ao bf16.
// ---------------------------------------------------------------------------
__global__ __launch_bounds__(256) void attn_cand(
    const unsigned short* __restrict__ qkv, const unsigned char* __restrict__ mask,
    unsigned short* __restrict__ ao) {
  const int bk = blockIdx.x;
  const int b = bk >> 10;
  const int kk = bk & 1023;
  const int h = threadIdx.x >> 6;
  const int lane = threadIdx.x & 63;
  const size_t rowg = (size_t)b * Sc * 768 + h * 64;
  const size_t rowc = rowg + (size_t)(2 + kk) * 768;
  const float qc = bf2f(qkv[rowc + lane]);
  float p0 = qc * bf2f(qkv[rowg + 256 + lane]);
  float p1 = qc * bf2f(qkv[rowg + 256 + 768 + lane]);
  float p2 = qc * bf2f(qkv[rowc + 256 + lane]);
#pragma unroll
  for (int off = 32; off > 0; off >>= 1) {
    p0 += __shfl_xor(p0, off, 64);
    p1 += __shfl_xor(p1, off, 64);
    p2 += __shfl_xor(p2, off, 64);
  }
  const bool pad = (mask[b * Kc + kk] == 0);
  const float s0 = p0 * SCALEc;
  const float s1 = p1 * SCALEc;
  const float s2 = pad ? -INFINITY : p2 * SCALEc;
  const float m = fmaxf(fmaxf(s0, s1), s2);
  const float e0 = expf(s0 - m);
  const float e1 = expf(s1 - m);
  const float e2 = pad ? 0.0f : expf(s2 - m);
  const float inv = 1.0f / (e0 + e1 + e2);
  const float o = (e0 * bf2f(qkv[rowg + 512 + lane]) +
                   e1 * bf2f(qkv[rowg + 512 + 768 + lane]) +
                   e2 * bf2f(qkv[rowc + 512 + lane])) * inv;
  ao[((size_t)b * Sc + 2 + kk) * Dc + h * 64 + lane] = f2bf(o);
}

// ---------------------------------------------------------------------------
// Head: LN + dot(head_w) + head_b, mask-scatter into out (B, 1025). bf16 x.
// ---------------------------------------------------------------------------
__global__ __launch_bounds__(256) void head_kernel(
    const unsigned short* __restrict__ x, const float* __restrict__ lnw,
    const float* __restrict__ lnb, const float* __restrict__ hw,
    const float* __restrict__ hb, const unsigned char* __restrict__ mask,
    float* __restrict__ out) {
  const int gw = blockIdx.x * 4 + (threadIdx.x >> 6);
  const int lane = threadIdx.x & 63;
  if (gw >= Bc * 1025) return;
  const int b = gw / 1025;
  const int j = gw - b * 1025;
  const int s = 1 + j;
  const unsigned short* xr = x + ((size_t)b * Sc + s) * Dc;
  ushort4 xv = *(const ushort4*)(xr + lane * 4);
  const float v0 = bf2f(xv.x), v1 = bf2f(xv.y), v2 = bf2f(xv.z), v3 = bf2f(xv.w);
  float su = v0 + v1 + v2 + v3;
  float sq = v0 * v0 + v1 * v1 + v2 * v2 + v3 * v3;
  su = wave_sum(su);
  sq = wave_sum(sq);
  const float mean = su * (1.0f / Dc);
  const float var = sq * (1.0f / Dc) - mean * mean;
  const float rs = rsqrtf(var + EPSc);
  float4 wv = *(const float4*)(lnw + lane * 4);
  float4 bv = *(const float4*)(lnb + lane * 4);
  float4 hv = *(const float4*)(hw + lane * 4);
  float d = ((v0 - mean) * rs * wv.x + bv.x) * hv.x +
            ((v1 - mean) * rs * wv.y + bv.y) * hv.y +
            ((v2 - mean) * rs * wv.z + bv.z) * hv.z +
            ((v3 - mean) * rs * wv.w + bv.w) * hv.w;
  d = wave_sum(d);
  if (lane == 0) {
    const float logit = d + hb[0];
    float res;
    if (j == 0) res = logit;
    else res = (mask[b * Kc + (j - 1)] != 0) ? logit : NEG_OUT;
    out[(size_t)b * 1025 + j] = res;
  }
}

// ---------------------------------------------------------------------------
extern "C" void kernel_launch(void* const* d_in, const int* in_sizes, int n_in,
                              void* d_out, int out_size, void* d_ws,
                              size_t ws_size, hipStream_t stream) {
  const float* query = (const float*)d_in[0];
  const float* cands = (const float*)d_in[1];
  const unsigned char* mask = (const unsigned char*)d_in[2];
  const float* qp_w = (const float*)d_in[3];
  const float* qp_b = (const float*)d_in[4];
  const float* cp_w = (const float*)d_in[5];
  const float* cp_b = (const float*)d_in[6];
  const float* dustbin = (const float*)d_in[7];
  const float* type_emb = (const float*)d_in[8];
  const float* ln1_w = (const float*)d_in[9];
  const float* ln1_b = (const float*)d_in[10];
  const float* ln2_w = (const float*)d_in[11];
  const float* ln2_b = (const float*)d_in[12];
  const float* Wq = (const float*)d_in[13];
  const float* bq = (const float*)d_in[14];
  const float* Wk = (const float*)d_in[15];
  const float* bk = (const float*)d_in[16];
  const float* Wv = (const float*)d_in[17];
  const float* bv = (const float*)d_in[18];
  const float* Wo = (const float*)d_in[19];
  const float* bo = (const float*)d_in[20];
  const float* f1w = (const float*)d_in[21];
  const float* f1b = (const float*)d_in[22];
  const float* f2w = (const float*)d_in[23];
  const float* f2b = (const float*)d_in[24];
  const float* hlw = (const float*)d_in[25];
  const float* hlb = (const float*)d_in[26];
  const float* hw = (const float*)d_in[27];
  const float* hb = (const float*)d_in[28];
  float* out = (float*)d_out;

  const size_t XSZ = (size_t)Bc * Sc * Dc;       // 16,809,984
  const size_t FFSZ = (size_t)Bc * Sc * FFc;     // >= BS*768

  char* p = (char*)d_ws;
  unsigned short* x = (unsigned short*)p;   p += XSZ * 2;   // bf16 residual
  unsigned short* y = (unsigned short*)p;   p += XSZ * 2;
  unsigned short* ao = (unsigned short*)p;  p += XSZ * 2;
  unsigned short* big = (unsigned short*)p; p += FFSZ * 2;
  unsigned short* qkv = big;                // [BS][768], overlapped with ff
  unsigned short* ff = big;                 // [BS][1024]
  unsigned short* cpw_b = (unsigned short*)p;      // 256x512
  unsigned short* qkvw_b = cpw_b + 131072;          // [L][768][256]
  unsigned short* Wo_b = qkvw_b + 2 * 768 * 256;    // [L][256][256]
  unsigned short* f1_b = Wo_b + 131072;             // [L][1024][256]
  unsigned short* f2_b = f1_b + 524288;             // [L][256][1024]
  float* qkvb = (float*)(f2_b + 524288);            // [L][768]

  const int BS = Bc * Sc;  // 65664 = 513*128
  auto sgrid = [](int MB, int NB) { return (unsigned)(NB * (((MB + 7) >> 3) << 3)); };

  CastTab t;
  t.src[0] = cp_w;  t.dst[0] = cpw_b; t.n4[0] = 131072 / 4;
  t.src[1] = Wo;    t.dst[1] = Wo_b;  t.n4[1] = 131072 / 4;
  t.src[2] = f1w;   t.dst[2] = f1_b;  t.n4[2] = 524288 / 4;
  t.src[3] = f2w;   t.dst[3] = f2_b;  t.n4[3] = 524288 / 4;
  for (int l = 0; l < 2; ++l) {
    t.src[4 + l * 3 + 0] = Wq + l * 65536;
    t.src[4 + l * 3 + 1] = Wk + l * 65536;
    t.src[4 + l * 3 + 2] = Wv + l * 65536;
    t.dst[4 + l * 3 + 0] = qkvw_b + l * 196608 + 0 * 65536;
    t.dst[4 + l * 3 + 1] = qkvw_b + l * 196608 + 1 * 65536;
    t.dst[4 + l * 3 + 2] = qkvw_b + l * 196608 + 2 * 65536;
    t.n4[4 + l * 3 + 0] = 65536 / 4;
    t.n4[4 + l * 3 + 1] = 65536 / 4;
    t.n4[4 + l * 3 + 2] = 65536 / 4;
  }
  cast_multi<<<dim3(128, 10), 256, 0, stream>>>(t);
  bias_concat<<<6, 256, 0, stream>>>(bq, bk, bv, qkvb);

  // Embed: candidates (fp32, fused cast) -> x rows [2,1026). N=256 -> NB=1.
  gemm_mfma<1, 1, 1><<<sgrid(512, 1), 256, 0, stream>>>(
      cands, cpw_b, cp_b, type_emb + 2 * Dc, x, Dc, Cc, Dc, 512, 1);
  embed_qd<<<Bc, 256, 0, stream>>>(query, qp_w, qp_b, dustbin, type_emb, x);

  for (int l = 0; l < 2; ++l) {
    ln_kernel<<<BS / 4, 256, 0, stream>>>(x, ln1_w + l * Dc, ln1_b + l * Dc, y, BS);
    // Fused QKV: N=768 -> NB=3.
    gemm_mfma<4, 0, 0><<<sgrid(513, 3), 256, 0, stream>>>(
        y, qkvw_b + l * 196608, qkvb + l * 768, nullptr, qkv, 768, Dc, 768, 513, 3);
    attn_global<<<dim3(Bc, Hc), 256, 0, stream>>>(qkv, mask, ao);
    attn_cand<<<Bc * Kc, 256, 0, stream>>>(qkv, mask, ao);
    // Wo: N=256 -> NB=1.
    gemm_mfma<2, 0, 0><<<sgrid(513, 1), 256, 0, stream>>>(
        ao, Wo_b + l * 65536, bo + l * Dc, x, x, Dc, Dc, Dc, 513, 1);
    ln_kernel<<<BS / 4, 256, 0, stream>>>(x, ln2_w + l * Dc, ln2_b + l * Dc, y, BS);
    // FF1: N=1024 -> NB=4.
    gemm_mfma<3, 0, 0><<<sgrid(513, 4), 256, 0, stream>>>(
        y, f1_b + l * 524288 / 2, f1b + l * FFc, nullptr, ff, FFc, Dc, FFc, 513, 4);
    // FF2: N=256 -> NB=1, K=1024.
    gemm_mfma<2, 0, 0><<<sgrid(513, 1), 256, 0, stream>>>(
        ff, f2_b + l * 524288 / 2, f2b + l * Dc, x, x, Dc, FFc, Dc, 513, 1);
  }

  head_kernel<<<(Bc * 1025 + 3) / 4, 256, 0, stream>>>(x, hlw, hlb, hw, hb, mask, out);
}

// Round 6
// 956.236 us; speedup vs baseline: 1.2446x; 1.2446x over previous
//
#include <hip/hip_runtime.h>
#include <math.h>

// Model constants
static constexpr int Bc = 64;
static constexpr int Kc = 1024;
static constexpr int Cc = 512;
static constexpr int Dc = 256;
static constexpr int Hc = 4;
static constexpr int Sc = 1026;       // 2 + K
static constexpr int FFc = 1024;
static constexpr float EPSc = 1e-5f;
static constexpr float SCALEc = 0.125f;   // 1/sqrt(64)
static constexpr float NEG_OUT = -1.0e30f;  // finite stand-in for -inf

typedef __attribute__((ext_vector_type(8))) short short8;
typedef __attribute__((ext_vector_type(8))) unsigned short u16x8;
typedef __attribute__((ext_vector_type(4))) float f32x4;

__device__ __forceinline__ float bf2f(unsigned short u) {
  union { float f; unsigned int i; } c; c.i = ((unsigned int)u) << 16; return c.f;
}
__device__ __forceinline__ unsigned short f2bf(float f) {
  union { float f; unsigned int i; } c; c.f = f;
  unsigned int i = c.i;
  unsigned int r = (i + 0x7fffu + ((i >> 16) & 1u)) >> 16;  // RNE
  return (unsigned short)r;
}
// Packed f32x2 -> bf16x2 (RNE), 1 instruction. Low16 = a, high16 = b.
__device__ __forceinline__ unsigned int cvt_pk_bf16(float a, float b) {
  unsigned int d;
  asm("v_cvt_pk_bf16_f32 %0, %1, %2" : "=v"(d) : "v"(a), "v"(b));
  return d;
}

__device__ __forceinline__ float wave_sum(float v) {
#pragma unroll
  for (int off = 32; off > 0; off >>= 1) v += __shfl_xor(v, off, 64);
  return v;
}
__device__ __forceinline__ float wave_max(float v) {
#pragma unroll
  for (int off = 32; off > 0; off >>= 1) v = fmaxf(v, __shfl_xor(v, off, 64));
  return v;
}

__device__ __forceinline__ void async_ld16(const unsigned short* g, unsigned short* l) {
  __builtin_amdgcn_global_load_lds(
      (const __attribute__((address_space(1))) void*)g,
      (__attribute__((address_space(3))) void*)l, 16, 0, 0);
}

// Fast GELU, tanh-form (err ~1e-3 rel, below bf16 rounding).
__device__ __forceinline__ float gelu_fast(float u) {
  const float z = u * fmaf(u * u, 0.07135481627f, 1.5957691216f);
  return __fdividef(u, 1.0f + __expf(-z));
}

// ---------------------------------------------------------------------------
// bf16 MFMA GEMM, BK=32, XCD-aware 1D grid swizzle. R3-VERIFIED CONFIG
// (128m x 128n, 48KB LDS, 3-buffer, counted vmcnt(4)) — best measured
// (999 us total, FF1 90.4 us). R5's 256-wide tile regressed (occupancy
// 19->10%, MfmaUtil 16->8.8): throughput here is resident-parallelism
// bound, so keep the narrow tile.
// A: [M][Kd] bf16 (CASTA=0) or fp32 (CASTA=1, cast fused into staging).
// W: [N][Kd] bf16. EPI: 1 +extraF[n]; 2 +bf16 residual extraB (in-place
// OK); 3 fast GELU; 4 bias only. Outputs bf16.
// MAP: 1 = candidate row scatter m -> (m>>10)*1026+2+(m&1023).
// ---------------------------------------------------------------------------
template <int EPI, int MAP, int CASTA>
__global__ __launch_bounds__(256) void gemm_mfma(
    const void* __restrict__ Av, const unsigned short* __restrict__ W,
    const float* __restrict__ bias, const void* extra,
    void* Cout, int N, int Kd, int ldc, int MB, int NB) {
  __shared__ unsigned short lds[24576];
  const int xcd = blockIdx.x & 7;
  const int slot = blockIdx.x >> 3;
  const int nb = slot % NB;
  const int mb = (slot / NB) * 8 + xcd;
  if (mb >= MB) return;
  const int m0 = mb * 128;
  const int n0 = nb * 128;
  const int tid = threadIdx.x;
  const int w = tid >> 6;
  const int lane = tid & 63;

  const unsigned short* A = (const unsigned short*)Av;
  const float* Af = (const float*)Av;

  const int srA[2] = {(w * 2 + 0) * 16 + (lane >> 2), (w * 2 + 1) * 16 + (lane >> 2)};
  const unsigned short* pA[2];
  const unsigned short* pB[2];
#pragma unroll
  for (int c = 0; c < 2; ++c) {
    const int kc = ((lane & 3) ^ ((srA[c] >> 1) & 3)) * 8;
    if (!CASTA) pA[c] = A + (size_t)(m0 + srA[c]) * Kd + kc;
    pB[c] = W + (size_t)(n0 + srA[c]) * Kd + kc;
  }
  const int lreg0 = (w * 2 + 0) * 512;
  const int lreg1 = (w * 2 + 1) * 512;

  f32x4 zero = {0.f, 0.f, 0.f, 0.f};
  f32x4 acc[4][4];
#pragma unroll
  for (int i = 0; i < 4; ++i)
#pragma unroll
    for (int j = 0; j < 4; ++j) acc[i][j] = zero;

  const int mrow = (w & 1) * 64;
  const int nrow = (w >> 1) * 64;
  const int l15 = lane & 15;
  const int quad = lane >> 4;
  const int koff = (quad ^ ((l15 >> 1) & 3)) * 16;

  auto stage = [&](int kk, int b) {
    if (CASTA) {
#pragma unroll
      for (int wi = 0; wi < 4; ++wi) {
        const int g = wi * 256 + tid;
        const int row = g >> 3;
        const int k4 = g & 7;
        const int phys =
            row * 32 + ((((k4 >> 1) ^ ((row >> 1) & 3))) << 3) + ((k4 & 1) << 2);
        const float4 a4 =
            *(const float4*)(Af + (size_t)(m0 + row) * Kd + kk + k4 * 4);
        uint2 o;
        o.x = cvt_pk_bf16(a4.x, a4.y);
        o.y = cvt_pk_bf16(a4.z, a4.w);
        *(uint2*)(&lds[b * 4096 + phys]) = o;
      }
    } else {
      async_ld16(pA[0] + kk, &lds[b * 4096 + lreg0]);
      async_ld16(pA[1] + kk, &lds[b * 4096 + lreg1]);
    }
    async_ld16(pB[0] + kk, &lds[12288 + b * 4096 + lreg0]);
    async_ld16(pB[1] + kk, &lds[12288 + b * 4096 + lreg1]);
  };

  auto compute_tile = [&](int cur) {
    const char* AsB = (const char*)&lds[cur * 4096];
    const char* WsB = (const char*)&lds[12288 + cur * 4096];
    short8 af[4], bfr[4];
#pragma unroll
    for (int i = 0; i < 4; ++i)
      af[i] = *(const short8*)(AsB + (size_t)(mrow + i * 16 + l15) * 64 + koff);
#pragma unroll
    for (int j = 0; j < 4; ++j)
      bfr[j] = *(const short8*)(WsB + (size_t)(nrow + j * 16 + l15) * 64 + koff);
#pragma unroll
    for (int i = 0; i < 4; ++i)
#pragma unroll
      for (int j = 0; j < 4; ++j)
        acc[i][j] = __builtin_amdgcn_mfma_f32_16x16x32_bf16(bfr[j], af[i],
                                                            acc[i][j], 0, 0, 0);
  };

  const int niter = Kd >> 5;
  if (CASTA) {
    stage(0, 0);
    for (int it = 0; it < niter; ++it) {
      const int cur = it & 1;
      __syncthreads();
      if (it + 1 < niter) stage((it + 1) << 5, cur ^ 1);
      compute_tile(cur);
    }
  } else {
    stage(0, 0);
    stage(32, 1);
    int cur = 0;
    for (int it = 0; it < niter; ++it) {
      if (it + 1 < niter)
        asm volatile("s_waitcnt vmcnt(4)" ::: "memory");
      else
        asm volatile("s_waitcnt vmcnt(0)" ::: "memory");
      asm volatile("s_waitcnt lgkmcnt(0)" ::: "memory");
      __builtin_amdgcn_s_barrier();
      if (it + 2 < niter) {
        int b2 = cur + 2; if (b2 >= 3) b2 -= 3;
        stage((it + 2) << 5, b2);
      }
      compute_tile(cur);
      cur = (cur == 2) ? 0 : cur + 1;
    }
  }

  // ---- Epilogue ----
  const float* extraF = (const float*)extra;
  const unsigned short* extraB = (const unsigned short*)extra;
  float4 bj[4];
#pragma unroll
  for (int j = 0; j < 4; ++j) {
    const int n = n0 + nrow + j * 16 + quad * 4;
    float4 t4 = *(const float4*)(bias + n);
    if (EPI == 1) {
      const float4 e4 = *(const float4*)(extraF + n);
      t4.x += e4.x; t4.y += e4.y; t4.z += e4.z; t4.w += e4.w;
    }
    bj[j] = t4;
  }
  __syncthreads();
#pragma unroll
  for (int i = 0; i < 4; ++i) {
    const int m = mrow + i * 16 + l15;
    const int swz = (m & 7) << 1;
#pragma unroll
    for (int j = 0; j < 4; ++j) {
      float v0 = acc[i][j][0] + bj[j].x;
      float v1 = acc[i][j][1] + bj[j].y;
      float v2 = acc[i][j][2] + bj[j].z;
      float v3 = acc[i][j][3] + bj[j].w;
      if (EPI == 3) {
        v0 = gelu_fast(v0); v1 = gelu_fast(v1);
        v2 = gelu_fast(v2); v3 = gelu_fast(v3);
      }
      uint2 pk;
      pk.x = cvt_pk_bf16(v0, v1);
      pk.y = cvt_pk_bf16(v2, v3);
      const int g = ((nrow + j * 16 + quad * 4) >> 2) ^ swz;
      *(uint2*)(&lds[m * 128 + g * 4]) = pk;
    }
  }
  __syncthreads();
  unsigned short* outb = (unsigned short*)Cout;
#pragma unroll
  for (int c8 = 0; c8 < 8; ++c8) {
    const int idx = c8 * 256 + tid;
    const int row = idx >> 4;
    const int cc = idx & 15;
    const int gsr = (2 * cc) ^ ((row & 7) << 1);
    u16x8 val = *(const u16x8*)(&lds[row * 128 + gsr * 4]);
    const int col = cc * 8;
    const int m = m0 + row;
    const size_t orow =
        (MAP == 1) ? ((size_t)(m >> 10) * Sc + 2 + (m & 1023)) : (size_t)m;
    const size_t go = orow * (size_t)ldc + n0 + col;
    if (EPI == 2) {
      u16x8 rv = *(const u16x8*)(extraB + go);
      unsigned int* vp = (unsigned int*)&val;
#pragma unroll
      for (int e = 0; e < 4; ++e) {
        const float a0 = bf2f(val[2 * e]) + bf2f(rv[2 * e]);
        const float a1 = bf2f(val[2 * e + 1]) + bf2f(rv[2 * e + 1]);
        vp[e] = cvt_pk_bf16(a0, a1);
      }
    }
    *(u16x8*)(outb + go) = val;
  }
}

// ---------------------------------------------------------------------------
// Mega weight cast: one dispatch, 10 (src fp32, dst bf16, n4) entries.
// ---------------------------------------------------------------------------
struct CastTab {
  const float* src[10];
  unsigned short* dst[10];
  int n4[10];
};
__global__ __launch_bounds__(256) void cast_multi(CastTab t) {
  const int e = blockIdx.y;
  const int n4 = t.n4[e];
  const float4* s = (const float4*)t.src[e];
  uint2* d = (uint2*)t.dst[e];
  for (int i = blockIdx.x * 256 + threadIdx.x; i < n4; i += gridDim.x * 256) {
    float4 f = s[i];
    uint2 o;
    o.x = cvt_pk_bf16(f.x, f.y);
    o.y = cvt_pk_bf16(f.z, f.w);
    d[i] = o;
  }
}

// Concatenate bq|bk|bv (fp32) per layer into qkvb [L][768].
__global__ __launch_bounds__(256) void bias_concat(const float* bq, const float* bk,
                                                   const float* bv, float* qkvb) {
  const int i = blockIdx.x * 256 + threadIdx.x;
  if (i >= 2 * 768) return;
  const int l = i / 768;
  const int j = i - l * 768;
  float v;
  if (j < 256) v = bq[l * 256 + j];
  else if (j < 512) v = bk[l * 256 + j - 256];
  else v = bv[l * 256 + j - 512];
  qkvb[i] = v;
}

// ---------------------------------------------------------------------------
// Query projection (row s=0) + dustbin token (row s=1) -> bf16 x.
// ---------------------------------------------------------------------------
__global__ __launch_bounds__(256) void embed_qd(
    const float* __restrict__ qin, const float* __restrict__ qp_w,
    const float* __restrict__ qp_b, const float* __restrict__ dustbin,
    const float* __restrict__ type_emb, unsigned short* __restrict__ x) {
  const int b = blockIdx.x;
  const int d = threadIdx.x;
  __shared__ __align__(16) float qs[512];
  qs[d] = qin[b * 512 + d];
  qs[d + 256] = qin[b * 512 + 256 + d];
  __syncthreads();
  float acc = 0.0f;
  const float* wr = qp_w + (size_t)d * 512;
#pragma unroll 4
  for (int c = 0; c < 512; c += 4) {
    float4 w4 = *(const float4*)(wr + c);
    acc = fmaf(qs[c], w4.x, acc);
    acc = fmaf(qs[c + 1], w4.y, acc);
    acc = fmaf(qs[c + 2], w4.z, acc);
    acc = fmaf(qs[c + 3], w4.w, acc);
  }
  const size_t base = (size_t)b * Sc * Dc;
  x[base + d] = f2bf(acc + qp_b[d] + type_emb[d]);
  x[base + Dc + d] = f2bf(dustbin[d] + type_emb[Dc + d]);
}

// ---------------------------------------------------------------------------
// LayerNorm: bf16 in, bf16 out. R14: 16 rows/block (4 waves x 4-row loop),
// gamma/beta hoisted -> 4104 blocks instead of 16416.
// ---------------------------------------------------------------------------
__global__ __launch_bounds__(256) void ln_kernel(
    const unsigned short* __restrict__ x, const float* __restrict__ w,
    const float* __restrict__ b, unsigned short* __restrict__ y, int nrows) {
  const int wave = threadIdx.x >> 6;
  const int lane = threadIdx.x & 63;
  const int row0 = blockIdx.x * 16 + wave * 4;
  const float4 wv = *(const float4*)(w + lane * 4);
  const float4 bv = *(const float4*)(b + lane * 4);
#pragma unroll
  for (int r = 0; r < 4; ++r) {
    const int row = row0 + r;
    if (row >= nrows) return;
    const unsigned short* xr = x + (size_t)row * Dc;
    ushort4 xv = *(const ushort4*)(xr + lane * 4);
    const float v0 = bf2f(xv.x), v1 = bf2f(xv.y), v2 = bf2f(xv.z), v3 = bf2f(xv.w);
    float s = v0 + v1 + v2 + v3;
    float sq = v0 * v0 + v1 * v1 + v2 * v2 + v3 * v3;
    s = wave_sum(s);
    sq = wave_sum(sq);
    const float mean = s * (1.0f / Dc);
    const float var = sq * (1.0f / Dc) - mean * mean;
    const float rs = rsqrtf(var + EPSc);
    uint2 o;
    o.x = cvt_pk_bf16((v0 - mean) * rs * wv.x + bv.x,
                      (v1 - mean) * rs * wv.y + bv.y);
    o.y = cvt_pk_bf16((v2 - mean) * rs * wv.z + bv.z,
                      (v3 - mean) * rs * wv.w + bv.w);
    *(uint2*)(y + (size_t)row * Dc + lane * 4) = o;
  }
}

// ---------------------------------------------------------------------------
// Global-token attention over fused qkv [BS][768] bf16 (q|k|v). Out ao bf16.
// ---------------------------------------------------------------------------
__global__ __launch_bounds__(256) void attn_global(
    const unsigned short* __restrict__ qkv, const unsigned char* __restrict__ mask,
    unsigned short* __restrict__ ao) {
  const int b = blockIdx.x;
  const int h = blockIdx.y;
  const int tid = threadIdx.x;
  const int wv = tid >> 6;
  const int lane = tid & 63;
  __shared__ float q0s[64], q1s[64];
  __shared__ float sc0[Sc], sc1[Sc];
  __shared__ float rbuf[4][2];
  __shared__ float obuf[2][4][64];
  const size_t base = (size_t)b * Sc * 768 + h * 64;
  if (tid < 64) {
    q0s[tid] = bf2f(qkv[base + tid]);
    q1s[tid] = bf2f(qkv[base + 768 + tid]);
  }
  __syncthreads();

  float lm0 = -INFINITY, lm1 = -INFINITY;
  for (int s = tid; s < Sc; s += 256) {
    const unsigned short* kr = qkv + base + 256 + (size_t)s * 768;
    float d0 = 0.0f, d1 = 0.0f;
#pragma unroll
    for (int c = 0; c < 64; c += 8) {
      u16x8 kv = *(const u16x8*)(kr + c);
#pragma unroll
      for (int e = 0; e < 8; ++e) {
        const float kf = bf2f(kv[e]);
        d0 = fmaf(q0s[c + e], kf, d0);
        d1 = fmaf(q1s[c + e], kf, d1);
      }
    }
    const bool pad = (s >= 2) && (mask[b * Kc + (s - 2)] == 0);
    const float s0 = pad ? -INFINITY : d0 * SCALEc;
    const float s1 = pad ? -INFINITY : d1 * SCALEc;
    sc0[s] = s0; sc1[s] = s1;
    lm0 = fmaxf(lm0, s0); lm1 = fmaxf(lm1, s1);
  }
  lm0 = wave_max(lm0);
  lm1 = wave_max(lm1);
  if (lane == 0) { rbuf[wv][0] = lm0; rbuf[wv][1] = lm1; }
  __syncthreads();
  const float m0 = fmaxf(fmaxf(rbuf[0][0], rbuf[1][0]), fmaxf(rbuf[2][0], rbuf[3][0]));
  const float m1 = fmaxf(fmaxf(rbuf[0][1], rbuf[1][1]), fmaxf(rbuf[2][1], rbuf[3][1]));
  float ls0 = 0.0f, ls1 = 0.0f;
  for (int s = tid; s < Sc; s += 256) {
    const float e0 = expf(sc0[s] - m0);
    const float e1 = expf(sc1[s] - m1);
    sc0[s] = e0; sc1[s] = e1;
    ls0 += e0; ls1 += e1;
  }
  ls0 = wave_sum(ls0);
  ls1 = wave_sum(ls1);
  __syncthreads();
  if (lane == 0) { rbuf[wv][0] = ls0; rbuf[wv][1] = ls1; }
  __syncthreads();
  const float t0 = rbuf[0][0] + rbuf[1][0] + rbuf[2][0] + rbuf[3][0];
  const float t1 = rbuf[0][1] + rbuf[1][1] + rbuf[2][1] + rbuf[3][1];
  float o0 = 0.0f, o1 = 0.0f;
  for (int s = wv; s < Sc; s += 4) {
    const float vvv = bf2f(qkv[base + 512 + (size_t)s * 768 + lane]);
    o0 = fmaf(sc0[s], vvv, o0);
    o1 = fmaf(sc1[s], vvv, o1);
  }
  obuf[0][wv][lane] = o0;
  obuf[1][wv][lane] = o1;
  __syncthreads();
  if (wv == 0) {
    const float a0 = obuf[0][0][lane] + obuf[0][1][lane] + obuf[0][2][lane] + obuf[0][3][lane];
    const float a1 = obuf[1][0][lane] + obuf[1][1][lane] + obuf[1][2][lane] + obuf[1][3][lane];
    const size_t ob = ((size_t)b * Sc) * Dc + h * 64;
    ao[ob + lane] = f2bf(a0 / t0);
    ao[ob + Dc + lane] = f2bf(a1 / t1);
  }
}

// ---------------------------------------------------------------------------
// Candidate attention. R14 restructure: was 65536 blocks x 18 serialized
// shuffles per single candidate (latency-bound, ~256 block-rounds/CU).
// Now 512 blocks (b x 8); wave = head; 16 lanes x 4 dims per candidate
// (ushort4 loads), 4 candidates per wave-iter, 32 iters; global K/V rows
// hoisted to registers; 12 shuffles per 4 candidates.
// ---------------------------------------------------------------------------
__global__ __launch_bounds__(256) void attn_cand(
    const unsigned short* __restrict__ qkv, const unsigned char* __restrict__ mask,
    unsigned short* __restrict__ ao) {
  const int b = blockIdx.x >> 3;
  const int k0 = (blockIdx.x & 7) << 7;    // 128 candidates per block
  const int h = threadIdx.x >> 6;
  const int lane = threadIdx.x & 63;
  const int c4 = lane >> 4;                // candidate-in-group 0..3
  const int l16 = lane & 15;               // dim quad: dims l16*4..+4
  const size_t bbase = (size_t)b * Sc * 768;
  const unsigned short* gp = qkv + bbase + h * 64 + l16 * 4;
  float k0f[4], k1f[4], v0f[4], v1f[4];
  {
    const ushort4 a = *(const ushort4*)(gp + 256);
    const ushort4 c = *(const ushort4*)(gp + 256 + 768);
    const ushort4 d = *(const ushort4*)(gp + 512);
    const ushort4 e = *(const ushort4*)(gp + 512 + 768);
    k0f[0] = bf2f(a.x); k0f[1] = bf2f(a.y); k0f[2] = bf2f(a.z); k0f[3] = bf2f(a.w);
    k1f[0] = bf2f(c.x); k1f[1] = bf2f(c.y); k1f[2] = bf2f(c.z); k1f[3] = bf2f(c.w);
    v0f[0] = bf2f(d.x); v0f[1] = bf2f(d.y); v0f[2] = bf2f(d.z); v0f[3] = bf2f(d.w);
    v1f[0] = bf2f(e.x); v1f[1] = bf2f(e.y); v1f[2] = bf2f(e.z); v1f[3] = bf2f(e.w);
  }
  for (int t = 0; t < 32; ++t) {
    const int kk = k0 + t * 4 + c4;
    const unsigned short* cp =
        qkv + bbase + (size_t)(2 + kk) * 768 + h * 64 + l16 * 4;
    const ushort4 qv = *(const ushort4*)cp;
    const ushort4 kv = *(const ushort4*)(cp + 256);
    const ushort4 vv = *(const ushort4*)(cp + 512);
    const unsigned short* qp = (const unsigned short*)&qv;
    const unsigned short* kp = (const unsigned short*)&kv;
    const unsigned short* vp = (const unsigned short*)&vv;
    float p0 = 0.f, p1 = 0.f, p2 = 0.f;
#pragma unroll
    for (int e = 0; e < 4; ++e) {
      const float qf = bf2f(qp[e]);
      p0 = fmaf(qf, k0f[e], p0);
      p1 = fmaf(qf, k1f[e], p1);
      p2 = fmaf(qf, bf2f(kp[e]), p2);
    }
#pragma unroll
    for (int off = 1; off < 16; off <<= 1) {   // reduce within 16-lane group
      p0 += __shfl_xor(p0, off, 64);
      p1 += __shfl_xor(p1, off, 64);
      p2 += __shfl_xor(p2, off, 64);
    }
    const bool pad = (mask[b * Kc + kk] == 0);
    const float s0 = p0 * SCALEc;
    const float s1 = p1 * SCALEc;
    const float s2 = pad ? -INFINITY : p2 * SCALEc;
    const float m = fmaxf(fmaxf(s0, s1), s2);
    const float e0 = expf(s0 - m);
    const float e1 = expf(s1 - m);
    const float e2 = pad ? 0.0f : expf(s2 - m);
    const float inv = 1.0f / (e0 + e1 + e2);
    float o[4];
#pragma unroll
    for (int e = 0; e < 4; ++e)
      o[e] = (e0 * v0f[e] + e1 * v1f[e] + e2 * bf2f(vp[e])) * inv;
    uint2 pk;
    pk.x = cvt_pk_bf16(o[0], o[1]);
    pk.y = cvt_pk_bf16(o[2], o[3]);
    *(uint2*)(ao + ((size_t)b * Sc + 2 + kk) * Dc + h * 64 + l16 * 4) = pk;
  }
}

// ---------------------------------------------------------------------------
// Head: LN + dot(head_w) + head_b, mask-scatter into out (B, 1025).
// R14: 16 rows/block (4 waves x 4-row loop), weights hoisted -> 4100 blocks.
// ---------------------------------------------------------------------------
__global__ __launch_bounds__(256) void head_kernel(
    const unsigned short* __restrict__ x, const float* __restrict__ lnw,
    const float* __restrict__ lnb, const float* __restrict__ hw,
    const float* __restrict__ hb, const unsigned char* __restrict__ mask,
    float* __restrict__ out) {
  const int lane = threadIdx.x & 63;
  const int gw0 = blockIdx.x * 16 + (threadIdx.x >> 6) * 4;
  const float4 wv = *(const float4*)(lnw + lane * 4);
  const float4 bv = *(const float4*)(lnb + lane * 4);
  const float4 hv = *(const float4*)(hw + lane * 4);
  const float hb0 = hb[0];
#pragma unroll
  for (int r = 0; r < 4; ++r) {
    const int gw = gw0 + r;
    if (gw >= Bc * 1025) return;
    const int b = gw / 1025;
    const int j = gw - b * 1025;
    const int s = 1 + j;
    const unsigned short* xr = x + ((size_t)b * Sc + s) * Dc;
    ushort4 xv = *(const ushort4*)(xr + lane * 4);
    const float v0 = bf2f(xv.x), v1 = bf2f(xv.y), v2 = bf2f(xv.z), v3 = bf2f(xv.w);
    float su = v0 + v1 + v2 + v3;
    float sq = v0 * v0 + v1 * v1 + v2 * v2 + v3 * v3;
    su = wave_sum(su);
    sq = wave_sum(sq);
    const float mean = su * (1.0f / Dc);
    const float var = sq * (1.0f / Dc) - mean * mean;
    const float rs = rsqrtf(var + EPSc);
    float d = ((v0 - mean) * rs * wv.x + bv.x) * hv.x +
              ((v1 - mean) * rs * wv.y + bv.y) * hv.y +
              ((v2 - mean) * rs * wv.z + bv.z) * hv.z +
              ((v3 - mean) * rs * wv.w + bv.w) * hv.w;
    d = wave_sum(d);
    if (lane == 0) {
      const float logit = d + hb0;
      float res;
      if (j == 0) res = logit;
      else res = (mask[b * Kc + (j - 1)] != 0) ? logit : NEG_OUT;
      out[(size_t)b * 1025 + j] = res;
    }
  }
}

// ---------------------------------------------------------------------------
extern "C" void kernel_launch(void* const* d_in, const int* in_sizes, int n_in,
                              void* d_out, int out_size, void* d_ws,
                              size_t ws_size, hipStream_t stream) {
  const float* query = (const float*)d_in[0];
  const float* cands = (const float*)d_in[1];
  const unsigned char* mask = (const unsigned char*)d_in[2];
  const float* qp_w = (const float*)d_in[3];
  const float* qp_b = (const float*)d_in[4];
  const float* cp_w = (const float*)d_in[5];
  const float* cp_b = (const float*)d_in[6];
  const float* dustbin = (const float*)d_in[7];
  const float* type_emb = (const float*)d_in[8];
  const float* ln1_w = (const float*)d_in[9];
  const float* ln1_b = (const float*)d_in[10];
  const float* ln2_w = (const float*)d_in[11];
  const float* ln2_b = (const float*)d_in[12];
  const float* Wq = (const float*)d_in[13];
  const float* bq = (const float*)d_in[14];
  const float* Wk = (const float*)d_in[15];
  const float* bk = (const float*)d_in[16];
  const float* Wv = (const float*)d_in[17];
  const float* bv = (const float*)d_in[18];
  const float* Wo = (const float*)d_in[19];
  const float* bo = (const float*)d_in[20];
  const float* f1w = (const float*)d_in[21];
  const float* f1b = (const float*)d_in[22];
  const float* f2w = (const float*)d_in[23];
  const float* f2b = (const float*)d_in[24];
  const float* hlw = (const float*)d_in[25];
  const float* hlb = (const float*)d_in[26];
  const float* hw = (const float*)d_in[27];
  const float* hb = (const float*)d_in[28];
  float* out = (float*)d_out;

  const size_t XSZ = (size_t)Bc * Sc * Dc;       // 16,809,984
  const size_t FFSZ = (size_t)Bc * Sc * FFc;     // >= BS*768

  char* p = (char*)d_ws;
  unsigned short* x = (unsigned short*)p;   p += XSZ * 2;   // bf16 residual
  unsigned short* y = (unsigned short*)p;   p += XSZ * 2;
  unsigned short* ao = (unsigned short*)p;  p += XSZ * 2;
  unsigned short* big = (unsigned short*)p; p += FFSZ * 2;
  unsigned short* qkv = big;                // [BS][768], overlapped with ff
  unsigned short* ff = big;                 // [BS][1024]
  unsigned short* cpw_b = (unsigned short*)p;      // 256x512
  unsigned short* qkvw_b = cpw_b + 131072;          // [L][768][256]
  unsigned short* Wo_b = qkvw_b + 2 * 768 * 256;    // [L][256][256]
  unsigned short* f1_b = Wo_b + 131072;             // [L][1024][256]
  unsigned short* f2_b = f1_b + 524288;             // [L][256][1024]
  float* qkvb = (float*)(f2_b + 524288);            // [L][768]

  const int BS = Bc * Sc;  // 65664 = 513*128
  auto sgrid = [](int MB, int NB) { return (unsigned)(NB * (((MB + 7) >> 3) << 3)); };

  CastTab t;
  t.src[0] = cp_w;  t.dst[0] = cpw_b; t.n4[0] = 131072 / 4;
  t.src[1] = Wo;    t.dst[1] = Wo_b;  t.n4[1] = 131072 / 4;
  t.src[2] = f1w;   t.dst[2] = f1_b;  t.n4[2] = 524288 / 4;
  t.src[3] = f2w;   t.dst[3] = f2_b;  t.n4[3] = 524288 / 4;
  for (int l = 0; l < 2; ++l) {
    t.src[4 + l * 3 + 0] = Wq + l * 65536;
    t.src[4 + l * 3 + 1] = Wk + l * 65536;
    t.src[4 + l * 3 + 2] = Wv + l * 65536;
    t.dst[4 + l * 3 + 0] = qkvw_b + l * 196608 + 0 * 65536;
    t.dst[4 + l * 3 + 1] = qkvw_b + l * 196608 + 1 * 65536;
    t.dst[4 + l * 3 + 2] = qkvw_b + l * 196608 + 2 * 65536;
    t.n4[4 + l * 3 + 0] = 65536 / 4;
    t.n4[4 + l * 3 + 1] = 65536 / 4;
    t.n4[4 + l * 3 + 2] = 65536 / 4;
  }
  cast_multi<<<dim3(128, 10), 256, 0, stream>>>(t);
  bias_concat<<<6, 256, 0, stream>>>(bq, bk, bv, qkvb);

  // Embed: candidates (fp32, fused cast) -> x rows [2,1026); rows 0,1 direct.
  gemm_mfma<1, 1, 1><<<sgrid(512, 2), 256, 0, stream>>>(
      cands, cpw_b, cp_b, type_emb + 2 * Dc, x, Dc, Cc, Dc, 512, 2);
  embed_qd<<<Bc, 256, 0, stream>>>(query, qp_w, qp_b, dustbin, type_emb, x);

  for (int l = 0; l < 2; ++l) {
    ln_kernel<<<(BS + 15) / 16, 256, 0, stream>>>(x, ln1_w + l * Dc, ln1_b + l * Dc, y, BS);
    // Fused QKV: N=768, out pitch 768.
    gemm_mfma<4, 0, 0><<<sgrid(513, 6), 256, 0, stream>>>(
        y, qkvw_b + l * 196608, qkvb + l * 768, nullptr, qkv, 768, Dc, 768, 513, 6);
    attn_global<<<dim3(Bc, Hc), 256, 0, stream>>>(qkv, mask, ao);
    attn_cand<<<Bc * 8, 256, 0, stream>>>(qkv, mask, ao);
    gemm_mfma<2, 0, 0><<<sgrid(513, 2), 256, 0, stream>>>(
        ao, Wo_b + l * 65536, bo + l * Dc, x, x, Dc, Dc, Dc, 513, 2);
    ln_kernel<<<(BS + 15) / 16, 256, 0, stream>>>(x, ln2_w + l * Dc, ln2_b + l * Dc, y, BS);
    gemm_mfma<3, 0, 0><<<sgrid(513, 8), 256, 0, stream>>>(
        y, f1_b + l * 524288 / 2, f1b + l * FFc, nullptr, ff, FFc, Dc, FFc, 513, 8);
    gemm_mfma<2, 0, 0><<<sgrid(513, 2), 256, 0, stream>>>(
        ff, f2_b + l * 524288 / 2, f2b + l * Dc, x, x, Dc, FFc, Dc, 513, 2);
  }

  head_kernel<<<(Bc * 1025 + 15) / 16, 256, 0, stream>>>(x, hlw, hlb, hw, hb, mask, out);
}

// Round 7
// 902.583 us; speedup vs baseline: 1.3186x; 1.0594x over previous
//
#include <hip/hip_runtime.h>
#include <math.h>

// Model constants
static constexpr int Bc = 64;
static constexpr int Kc = 1024;
static constexpr int Cc = 512;
static constexpr int Dc = 256;
static constexpr int Hc = 4;
static constexpr int Sc = 1026;       // 2 + K
static constexpr int FFc = 1024;
static constexpr float EPSc = 1e-5f;
static constexpr float SCALEc = 0.125f;   // 1/sqrt(64)
static constexpr float NEG_OUT = -1.0e30f;  // finite stand-in for -inf

typedef __attribute__((ext_vector_type(8))) short short8;
typedef __attribute__((ext_vector_type(8))) unsigned short u16x8;
typedef __attribute__((ext_vector_type(4))) float f32x4;

__device__ __forceinline__ float bf2f(unsigned short u) {
  union { float f; unsigned int i; } c; c.i = ((unsigned int)u) << 16; return c.f;
}
__device__ __forceinline__ unsigned short f2bf(float f) {
  union { float f; unsigned int i; } c; c.f = f;
  unsigned int i = c.i;
  unsigned int r = (i + 0x7fffu + ((i >> 16) & 1u)) >> 16;  // RNE
  return (unsigned short)r;
}
// Packed f32x2 -> bf16x2 (RNE), 1 instruction. Low16 = a, high16 = b.
__device__ __forceinline__ unsigned int cvt_pk_bf16(float a, float b) {
  unsigned int d;
  asm("v_cvt_pk_bf16_f32 %0, %1, %2" : "=v"(d) : "v"(a), "v"(b));
  return d;
}

__device__ __forceinline__ float wave_sum(float v) {
#pragma unroll
  for (int off = 32; off > 0; off >>= 1) v += __shfl_xor(v, off, 64);
  return v;
}
__device__ __forceinline__ float wave_max(float v) {
#pragma unroll
  for (int off = 32; off > 0; off >>= 1) v = fmaxf(v, __shfl_xor(v, off, 64));
  return v;
}

__device__ __forceinline__ void async_ld16(const unsigned short* g, unsigned short* l) {
  __builtin_amdgcn_global_load_lds(
      (const __attribute__((address_space(1))) void*)g,
      (__attribute__((address_space(3))) void*)l, 16, 0, 0);
}

// Fast GELU, tanh-form, 7 VALU ops (log2e folded into constants; err ~1e-3
// rel, below bf16 rounding). sigma(z) computed as 1/(1+2^(u*(c0+c1*u^2))).
__device__ __forceinline__ float gelu_fast(float u) {
  const float m = fmaf(u * u, -0.10294916f, -2.3021174f);
  float e;
  asm("v_exp_f32 %0, %1" : "=v"(e) : "v"(u * m));   // 2^x
  return __fdividef(u, 1.0f + e);
}

// ---------------------------------------------------------------------------
// bf16 MFMA GEMM, BK=32, XCD-aware 1D grid swizzle. R3-VERIFIED CONFIG
// (128m x 128n, 48KB LDS, 3-buffer, counted vmcnt(4)).
// R15: (a) acc initialized with bias(+type-emb) BEFORE staging -- bias loads
// are consumed pre-DMA so the counted protocol sees only staging DMAs;
// epilogue add removed. (b) K-loop unrolled by 3 so the buffer index is a
// compile-time literal -> LDS addresses constant-folded (was ~30 VALU/iter
// of 3-way-select address recompute).
// A: [M][Kd] bf16 (CASTA=0) or fp32 (CASTA=1, cast fused into staging).
// W: [N][Kd] bf16. EPI: 1 +extraF[n]; 2 +bf16 residual extraB (in-place
// OK); 3 fast GELU; 4 bias only. Outputs bf16.
// MAP: 1 = candidate row scatter m -> (m>>10)*1026+2+(m&1023).
// ---------------------------------------------------------------------------
template <int EPI, int MAP, int CASTA>
__global__ __launch_bounds__(256) void gemm_mfma(
    const void* __restrict__ Av, const unsigned short* __restrict__ W,
    const float* __restrict__ bias, const void* extra,
    void* Cout, int N, int Kd, int ldc, int MB, int NB) {
  __shared__ unsigned short lds[24576];
  const int xcd = blockIdx.x & 7;
  const int slot = blockIdx.x >> 3;
  const int nb = slot % NB;
  const int mb = (slot / NB) * 8 + xcd;
  if (mb >= MB) return;
  const int m0 = mb * 128;
  const int n0 = nb * 128;
  const int tid = threadIdx.x;
  const int w = tid >> 6;
  const int lane = tid & 63;

  const unsigned short* A = (const unsigned short*)Av;
  const float* Af = (const float*)Av;

  const int srA[2] = {(w * 2 + 0) * 16 + (lane >> 2), (w * 2 + 1) * 16 + (lane >> 2)};
  const unsigned short* pA[2];
  const unsigned short* pB[2];
#pragma unroll
  for (int c = 0; c < 2; ++c) {
    const int kc = ((lane & 3) ^ ((srA[c] >> 1) & 3)) * 8;
    if (!CASTA) pA[c] = A + (size_t)(m0 + srA[c]) * Kd + kc;
    pB[c] = W + (size_t)(n0 + srA[c]) * Kd + kc;
  }
  const int lreg0 = (w * 2 + 0) * 512;
  const int lreg1 = (w * 2 + 1) * 512;

  const int mrow = (w & 1) * 64;
  const int nrow = (w >> 1) * 64;
  const int l15 = lane & 15;
  const int quad = lane >> 4;
  const int koff = (quad ^ ((l15 >> 1) & 3)) * 16;

  // Bias(+type-emb) loaded and CONSUMED into acc before any staging DMA is
  // issued, so the counted vmcnt protocol below sees only staging loads.
  const float* extraF = (const float*)extra;
  float4 bj[4];
#pragma unroll
  for (int j = 0; j < 4; ++j) {
    const int n = n0 + nrow + j * 16 + quad * 4;
    float4 t4 = *(const float4*)(bias + n);
    if (EPI == 1) {
      const float4 e4 = *(const float4*)(extraF + n);
      t4.x += e4.x; t4.y += e4.y; t4.z += e4.z; t4.w += e4.w;
    }
    bj[j] = t4;
  }
  f32x4 acc[4][4];
#pragma unroll
  for (int i = 0; i < 4; ++i)
#pragma unroll
    for (int j = 0; j < 4; ++j) {
      acc[i][j][0] = bj[j].x; acc[i][j][1] = bj[j].y;
      acc[i][j][2] = bj[j].z; acc[i][j][3] = bj[j].w;
    }

  auto stage = [&](int kk, int b) {
    if (CASTA) {
#pragma unroll
      for (int wi = 0; wi < 4; ++wi) {
        const int g = wi * 256 + tid;
        const int row = g >> 3;
        const int k4 = g & 7;
        const int phys =
            row * 32 + ((((k4 >> 1) ^ ((row >> 1) & 3))) << 3) + ((k4 & 1) << 2);
        const float4 a4 =
            *(const float4*)(Af + (size_t)(m0 + row) * Kd + kk + k4 * 4);
        uint2 o;
        o.x = cvt_pk_bf16(a4.x, a4.y);
        o.y = cvt_pk_bf16(a4.z, a4.w);
        *(uint2*)(&lds[b * 4096 + phys]) = o;
      }
    } else {
      async_ld16(pA[0] + kk, &lds[b * 4096 + lreg0]);
      async_ld16(pA[1] + kk, &lds[b * 4096 + lreg1]);
    }
    async_ld16(pB[0] + kk, &lds[12288 + b * 4096 + lreg0]);
    async_ld16(pB[1] + kk, &lds[12288 + b * 4096 + lreg1]);
  };

  auto compute_tile = [&](int cur) {
    const char* AsB = (const char*)&lds[cur * 4096];
    const char* WsB = (const char*)&lds[12288 + cur * 4096];
    short8 af[4], bfr[4];
#pragma unroll
    for (int i = 0; i < 4; ++i)
      af[i] = *(const short8*)(AsB + (size_t)(mrow + i * 16 + l15) * 64 + koff);
#pragma unroll
    for (int j = 0; j < 4; ++j)
      bfr[j] = *(const short8*)(WsB + (size_t)(nrow + j * 16 + l15) * 64 + koff);
#pragma unroll
    for (int i = 0; i < 4; ++i)
#pragma unroll
      for (int j = 0; j < 4; ++j)
        acc[i][j] = __builtin_amdgcn_mfma_f32_16x16x32_bf16(bfr[j], af[i],
                                                            acc[i][j], 0, 0, 0);
  };

  const int niter = Kd >> 5;
  if (CASTA) {
    stage(0, 0);
    for (int it = 0; it < niter; ++it) {
      const int cur = it & 1;
      __syncthreads();
      if (it + 1 < niter) stage((it + 1) << 5, cur ^ 1);
      compute_tile(cur);
    }
  } else {
    stage(0, 0);
    stage(32, 1);
    auto step = [&](int it, int c) {
      if (it + 1 < niter)
        asm volatile("s_waitcnt vmcnt(4)" ::: "memory");
      else
        asm volatile("s_waitcnt vmcnt(0)" ::: "memory");
      asm volatile("s_waitcnt lgkmcnt(0)" ::: "memory");
      __builtin_amdgcn_s_barrier();
      if (it + 2 < niter) {
        int b2 = c + 2; if (b2 >= 3) b2 -= 3;
        stage((it + 2) << 5, b2);
      }
      compute_tile(c);
    };
    int it = 0;
    for (; it + 3 <= niter; it += 3) {   // literal buffer idx -> const LDS addrs
      step(it + 0, 0);
      step(it + 1, 1);
      step(it + 2, 2);
    }
    for (; it < niter; ++it) step(it, it % 3);
  }

  // ---- Epilogue (bias already in acc) ----
  const unsigned short* extraB = (const unsigned short*)extra;
  __syncthreads();
#pragma unroll
  for (int i = 0; i < 4; ++i) {
    const int m = mrow + i * 16 + l15;
    const int swz = (m & 7) << 1;
#pragma unroll
    for (int j = 0; j < 4; ++j) {
      float v0 = acc[i][j][0];
      float v1 = acc[i][j][1];
      float v2 = acc[i][j][2];
      float v3 = acc[i][j][3];
      if (EPI == 3) {
        v0 = gelu_fast(v0); v1 = gelu_fast(v1);
        v2 = gelu_fast(v2); v3 = gelu_fast(v3);
      }
      uint2 pk;
      pk.x = cvt_pk_bf16(v0, v1);
      pk.y = cvt_pk_bf16(v2, v3);
      const int g = ((nrow + j * 16 + quad * 4) >> 2) ^ swz;
      *(uint2*)(&lds[m * 128 + g * 4]) = pk;
    }
  }
  __syncthreads();
  unsigned short* outb = (unsigned short*)Cout;
#pragma unroll
  for (int c8 = 0; c8 < 8; ++c8) {
    const int idx = c8 * 256 + tid;
    const int row = idx >> 4;
    const int cc = idx & 15;
    const int gsr = (2 * cc) ^ ((row & 7) << 1);
    u16x8 val = *(const u16x8*)(&lds[row * 128 + gsr * 4]);
    const int col = cc * 8;
    const int m = m0 + row;
    const size_t orow =
        (MAP == 1) ? ((size_t)(m >> 10) * Sc + 2 + (m & 1023)) : (size_t)m;
    const size_t go = orow * (size_t)ldc + n0 + col;
    if (EPI == 2) {
      u16x8 rv = *(const u16x8*)(extraB + go);
      unsigned int* vp = (unsigned int*)&val;
#pragma unroll
      for (int e = 0; e < 4; ++e) {
        const float a0 = bf2f(val[2 * e]) + bf2f(rv[2 * e]);
        const float a1 = bf2f(val[2 * e + 1]) + bf2f(rv[2 * e + 1]);
        vp[e] = cvt_pk_bf16(a0, a1);
      }
    }
    *(u16x8*)(outb + go) = val;
  }
}

// ---------------------------------------------------------------------------
// Mega weight cast: one dispatch, 10 (src fp32, dst bf16, n4) entries.
// ---------------------------------------------------------------------------
struct CastTab {
  const float* src[10];
  unsigned short* dst[10];
  int n4[10];
};
__global__ __launch_bounds__(256) void cast_multi(CastTab t) {
  const int e = blockIdx.y;
  const int n4 = t.n4[e];
  const float4* s = (const float4*)t.src[e];
  uint2* d = (uint2*)t.dst[e];
  for (int i = blockIdx.x * 256 + threadIdx.x; i < n4; i += gridDim.x * 256) {
    float4 f = s[i];
    uint2 o;
    o.x = cvt_pk_bf16(f.x, f.y);
    o.y = cvt_pk_bf16(f.z, f.w);
    d[i] = o;
  }
}

// Concatenate bq|bk|bv (fp32) per layer into qkvb [L][768].
__global__ __launch_bounds__(256) void bias_concat(const float* bq, const float* bk,
                                                   const float* bv, float* qkvb) {
  const int i = blockIdx.x * 256 + threadIdx.x;
  if (i >= 2 * 768) return;
  const int l = i / 768;
  const int j = i - l * 768;
  float v;
  if (j < 256) v = bq[l * 256 + j];
  else if (j < 512) v = bk[l * 256 + j - 256];
  else v = bv[l * 256 + j - 512];
  qkvb[i] = v;
}

// ---------------------------------------------------------------------------
// Query projection (row s=0) + dustbin token (row s=1) -> bf16 x.
// ---------------------------------------------------------------------------
__global__ __launch_bounds__(256) void embed_qd(
    const float* __restrict__ qin, const float* __restrict__ qp_w,
    const float* __restrict__ qp_b, const float* __restrict__ dustbin,
    const float* __restrict__ type_emb, unsigned short* __restrict__ x) {
  const int b = blockIdx.x;
  const int d = threadIdx.x;
  __shared__ __align__(16) float qs[512];
  qs[d] = qin[b * 512 + d];
  qs[d + 256] = qin[b * 512 + 256 + d];
  __syncthreads();
  float acc = 0.0f;
  const float* wr = qp_w + (size_t)d * 512;
#pragma unroll 4
  for (int c = 0; c < 512; c += 4) {
    float4 w4 = *(const float4*)(wr + c);
    acc = fmaf(qs[c], w4.x, acc);
    acc = fmaf(qs[c + 1], w4.y, acc);
    acc = fmaf(qs[c + 2], w4.z, acc);
    acc = fmaf(qs[c + 3], w4.w, acc);
  }
  const size_t base = (size_t)b * Sc * Dc;
  x[base + d] = f2bf(acc + qp_b[d] + type_emb[d]);
  x[base + Dc + d] = f2bf(dustbin[d] + type_emb[Dc + d]);
}

// ---------------------------------------------------------------------------
// LayerNorm: bf16 in, bf16 out. 16 rows/block (4 waves x 4-row loop).
// ---------------------------------------------------------------------------
__global__ __launch_bounds__(256) void ln_kernel(
    const unsigned short* __restrict__ x, const float* __restrict__ w,
    const float* __restrict__ b, unsigned short* __restrict__ y, int nrows) {
  const int wave = threadIdx.x >> 6;
  const int lane = threadIdx.x & 63;
  const int row0 = blockIdx.x * 16 + wave * 4;
  const float4 wv = *(const float4*)(w + lane * 4);
  const float4 bv = *(const float4*)(b + lane * 4);
#pragma unroll
  for (int r = 0; r < 4; ++r) {
    const int row = row0 + r;
    if (row >= nrows) return;
    const unsigned short* xr = x + (size_t)row * Dc;
    ushort4 xv = *(const ushort4*)(xr + lane * 4);
    const float v0 = bf2f(xv.x), v1 = bf2f(xv.y), v2 = bf2f(xv.z), v3 = bf2f(xv.w);
    float s = v0 + v1 + v2 + v3;
    float sq = v0 * v0 + v1 * v1 + v2 * v2 + v3 * v3;
    s = wave_sum(s);
    sq = wave_sum(sq);
    const float mean = s * (1.0f / Dc);
    const float var = sq * (1.0f / Dc) - mean * mean;
    const float rs = rsqrtf(var + EPSc);
    uint2 o;
    o.x = cvt_pk_bf16((v0 - mean) * rs * wv.x + bv.x,
                      (v1 - mean) * rs * wv.y + bv.y);
    o.y = cvt_pk_bf16((v2 - mean) * rs * wv.z + bv.z,
                      (v3 - mean) * rs * wv.w + bv.w);
    *(uint2*)(y + (size_t)row * Dc + lane * 4) = o;
  }
}

// ---------------------------------------------------------------------------
// Fused attention: blocks [0, 256) = global-token attention (long pole,
// scheduled first); blocks [256, 768) = candidate attention (R14 flat form).
// Merging removes one dispatch gap per layer.
// ---------------------------------------------------------------------------
__global__ __launch_bounds__(256) void attn_fused(
    const unsigned short* __restrict__ qkv, const unsigned char* __restrict__ mask,
    unsigned short* __restrict__ ao) {
  __shared__ float q0s[64], q1s[64];
  __shared__ float sc0[Sc], sc1[Sc];
  __shared__ float rbuf[4][2];
  __shared__ float obuf[2][4][64];
  const int tid = threadIdx.x;

  if (blockIdx.x < (unsigned)(Bc * Hc)) {
    // ---- global-token attention ----
    const int b = blockIdx.x >> 2;
    const int h = blockIdx.x & 3;
    const int wv = tid >> 6;
    const int lane = tid & 63;
    const size_t base = (size_t)b * Sc * 768 + h * 64;
    if (tid < 64) {
      q0s[tid] = bf2f(qkv[base + tid]);
      q1s[tid] = bf2f(qkv[base + 768 + tid]);
    }
    __syncthreads();

    float lm0 = -INFINITY, lm1 = -INFINITY;
    for (int s = tid; s < Sc; s += 256) {
      const unsigned short* kr = qkv + base + 256 + (size_t)s * 768;
      float d0 = 0.0f, d1 = 0.0f;
#pragma unroll
      for (int c = 0; c < 64; c += 8) {
        u16x8 kv = *(const u16x8*)(kr + c);
#pragma unroll
        for (int e = 0; e < 8; ++e) {
          const float kf = bf2f(kv[e]);
          d0 = fmaf(q0s[c + e], kf, d0);
          d1 = fmaf(q1s[c + e], kf, d1);
        }
      }
      const bool pad = (s >= 2) && (mask[b * Kc + (s - 2)] == 0);
      const float s0 = pad ? -INFINITY : d0 * SCALEc;
      const float s1 = pad ? -INFINITY : d1 * SCALEc;
      sc0[s] = s0; sc1[s] = s1;
      lm0 = fmaxf(lm0, s0); lm1 = fmaxf(lm1, s1);
    }
    lm0 = wave_max(lm0);
    lm1 = wave_max(lm1);
    if (lane == 0) { rbuf[wv][0] = lm0; rbuf[wv][1] = lm1; }
    __syncthreads();
    const float m0 = fmaxf(fmaxf(rbuf[0][0], rbuf[1][0]), fmaxf(rbuf[2][0], rbuf[3][0]));
    const float m1 = fmaxf(fmaxf(rbuf[0][1], rbuf[1][1]), fmaxf(rbuf[2][1], rbuf[3][1]));
    float ls0 = 0.0f, ls1 = 0.0f;
    for (int s = tid; s < Sc; s += 256) {
      const float e0 = expf(sc0[s] - m0);
      const float e1 = expf(sc1[s] - m1);
      sc0[s] = e0; sc1[s] = e1;
      ls0 += e0; ls1 += e1;
    }
    ls0 = wave_sum(ls0);
    ls1 = wave_sum(ls1);
    __syncthreads();
    if (lane == 0) { rbuf[wv][0] = ls0; rbuf[wv][1] = ls1; }
    __syncthreads();
    const float t0 = rbuf[0][0] + rbuf[1][0] + rbuf[2][0] + rbuf[3][0];
    const float t1 = rbuf[0][1] + rbuf[1][1] + rbuf[2][1] + rbuf[3][1];
    float o0 = 0.0f, o1 = 0.0f;
    for (int s = wv; s < Sc; s += 4) {
      const float vvv = bf2f(qkv[base + 512 + (size_t)s * 768 + lane]);
      o0 = fmaf(sc0[s], vvv, o0);
      o1 = fmaf(sc1[s], vvv, o1);
    }
    obuf[0][wv][lane] = o0;
    obuf[1][wv][lane] = o1;
    __syncthreads();
    if (wv == 0) {
      const float a0 = obuf[0][0][lane] + obuf[0][1][lane] + obuf[0][2][lane] + obuf[0][3][lane];
      const float a1 = obuf[1][0][lane] + obuf[1][1][lane] + obuf[1][2][lane] + obuf[1][3][lane];
      const size_t ob = ((size_t)b * Sc) * Dc + h * 64;
      ao[ob + lane] = f2bf(a0 / t0);
      ao[ob + Dc + lane] = f2bf(a1 / t1);
    }
    return;
  }

  // ---- candidate attention ----
  const int bk2 = blockIdx.x - Bc * Hc;
  const int b = bk2 >> 3;
  const int k0 = (bk2 & 7) << 7;           // 128 candidates per block
  const int h = tid >> 6;
  const int lane = tid & 63;
  const int c4 = lane >> 4;                // candidate-in-group 0..3
  const int l16 = lane & 15;               // dim quad: dims l16*4..+4
  const size_t bbase = (size_t)b * Sc * 768;
  const unsigned short* gp = qkv + bbase + h * 64 + l16 * 4;
  float k0f[4], k1f[4], v0f[4], v1f[4];
  {
    const ushort4 a = *(const ushort4*)(gp + 256);
    const ushort4 c = *(const ushort4*)(gp + 256 + 768);
    const ushort4 d = *(const ushort4*)(gp + 512);
    const ushort4 e = *(const ushort4*)(gp + 512 + 768);
    k0f[0] = bf2f(a.x); k0f[1] = bf2f(a.y); k0f[2] = bf2f(a.z); k0f[3] = bf2f(a.w);
    k1f[0] = bf2f(c.x); k1f[1] = bf2f(c.y); k1f[2] = bf2f(c.z); k1f[3] = bf2f(c.w);
    v0f[0] = bf2f(d.x); v0f[1] = bf2f(d.y); v0f[2] = bf2f(d.z); v0f[3] = bf2f(d.w);
    v1f[0] = bf2f(e.x); v1f[1] = bf2f(e.y); v1f[2] = bf2f(e.z); v1f[3] = bf2f(e.w);
  }
  for (int t = 0; t < 32; ++t) {
    const int kk = k0 + t * 4 + c4;
    const unsigned short* cp =
        qkv + bbase + (size_t)(2 + kk) * 768 + h * 64 + l16 * 4;
    const ushort4 qv = *(const ushort4*)cp;
    const ushort4 kv = *(const ushort4*)(cp + 256);
    const ushort4 vv = *(const ushort4*)(cp + 512);
    const unsigned short* qp = (const unsigned short*)&qv;
    const unsigned short* kp = (const unsigned short*)&kv;
    const unsigned short* vp = (const unsigned short*)&vv;
    float p0 = 0.f, p1 = 0.f, p2 = 0.f;
#pragma unroll
    for (int e = 0; e < 4; ++e) {
      const float qf = bf2f(qp[e]);
      p0 = fmaf(qf, k0f[e], p0);
      p1 = fmaf(qf, k1f[e], p1);
      p2 = fmaf(qf, bf2f(kp[e]), p2);
    }
#pragma unroll
    for (int off = 1; off < 16; off <<= 1) {   // reduce within 16-lane group
      p0 += __shfl_xor(p0, off, 64);
      p1 += __shfl_xor(p1, off, 64);
      p2 += __shfl_xor(p2, off, 64);
    }
    const bool pad = (mask[b * Kc + kk] == 0);
    const float s0 = p0 * SCALEc;
    const float s1 = p1 * SCALEc;
    const float s2 = pad ? -INFINITY : p2 * SCALEc;
    const float m = fmaxf(fmaxf(s0, s1), s2);
    const float e0 = expf(s0 - m);
    const float e1 = expf(s1 - m);
    const float e2 = pad ? 0.0f : expf(s2 - m);
    const float inv = 1.0f / (e0 + e1 + e2);
    float o[4];
#pragma unroll
    for (int e = 0; e < 4; ++e)
      o[e] = (e0 * v0f[e] + e1 * v1f[e] + e2 * bf2f(vp[e])) * inv;
    uint2 pk;
    pk.x = cvt_pk_bf16(o[0], o[1]);
    pk.y = cvt_pk_bf16(o[2], o[3]);
    *(uint2*)(ao + ((size_t)b * Sc + 2 + kk) * Dc + h * 64 + l16 * 4) = pk;
  }
}

// ---------------------------------------------------------------------------
// Head: LN + dot(head_w) + head_b, mask-scatter into out (B, 1025).
// 16 rows/block (4 waves x 4-row loop), weights hoisted.
// ---------------------------------------------------------------------------
__global__ __launch_bounds__(256) void head_kernel(
    const unsigned short* __restrict__ x, const float* __restrict__ lnw,
    const float* __restrict__ lnb, const float* __restrict__ hw,
    const float* __restrict__ hb, const unsigned char* __restrict__ mask,
    float* __restrict__ out) {
  const int lane = threadIdx.x & 63;
  const int gw0 = blockIdx.x * 16 + (threadIdx.x >> 6) * 4;
  const float4 wv = *(const float4*)(lnw + lane * 4);
  const float4 bv = *(const float4*)(lnb + lane * 4);
  const float4 hv = *(const float4*)(hw + lane * 4);
  const float hb0 = hb[0];
#pragma unroll
  for (int r = 0; r < 4; ++r) {
    const int gw = gw0 + r;
    if (gw >= Bc * 1025) return;
    const int b = gw / 1025;
    const int j = gw - b * 1025;
    const int s = 1 + j;
    const unsigned short* xr = x + ((size_t)b * Sc + s) * Dc;
    ushort4 xv = *(const ushort4*)(xr + lane * 4);
    const float v0 = bf2f(xv.x), v1 = bf2f(xv.y), v2 = bf2f(xv.z), v3 = bf2f(xv.w);
    float su = v0 + v1 + v2 + v3;
    float sq = v0 * v0 + v1 * v1 + v2 * v2 + v3 * v3;
    su = wave_sum(su);
    sq = wave_sum(sq);
    const float mean = su * (1.0f / Dc);
    const float var = sq * (1.0f / Dc) - mean * mean;
    const float rs = rsqrtf(var + EPSc);
    float d = ((v0 - mean) * rs * wv.x + bv.x) * hv.x +
              ((v1 - mean) * rs * wv.y + bv.y) * hv.y +
              ((v2 - mean) * rs * wv.z + bv.z) * hv.z +
              ((v3 - mean) * rs * wv.w + bv.w) * hv.w;
    d = wave_sum(d);
    if (lane == 0) {
      const float logit = d + hb0;
      float res;
      if (j == 0) res = logit;
      else res = (mask[b * Kc + (j - 1)] != 0) ? logit : NEG_OUT;
      out[(size_t)b * 1025 + j] = res;
    }
  }
}

// ---------------------------------------------------------------------------
extern "C" void kernel_launch(void* const* d_in, const int* in_sizes, int n_in,
                              void* d_out, int out_size, void* d_ws,
                              size_t ws_size, hipStream_t stream) {
  const float* query = (const float*)d_in[0];
  const float* cands = (const float*)d_in[1];
  const unsigned char* mask = (const unsigned char*)d_in[2];
  const float* qp_w = (const float*)d_in[3];
  const float* qp_b = (const float*)d_in[4];
  const float* cp_w = (const float*)d_in[5];
  const float* cp_b = (const float*)d_in[6];
  const float* dustbin = (const float*)d_in[7];
  const float* type_emb = (const float*)d_in[8];
  const float* ln1_w = (const float*)d_in[9];
  const float* ln1_b = (const float*)d_in[10];
  const float* ln2_w = (const float*)d_in[11];
  const float* ln2_b = (const float*)d_in[12];
  const float* Wq = (const float*)d_in[13];
  const float* bq = (const float*)d_in[14];
  const float* Wk = (const float*)d_in[15];
  const float* bk = (const float*)d_in[16];
  const float* Wv = (const float*)d_in[17];
  const float* bv = (const float*)d_in[18];
  const float* Wo = (const float*)d_in[19];
  const float* bo = (const float*)d_in[20];
  const float* f1w = (const float*)d_in[21];
  const float* f1b = (const float*)d_in[22];
  const float* f2w = (const float*)d_in[23];
  const float* f2b = (const float*)d_in[24];
  const float* hlw = (const float*)d_in[25];
  const float* hlb = (const float*)d_in[26];
  const float* hw = (const float*)d_in[27];
  const float* hb = (const float*)d_in[28];
  float* out = (float*)d_out;

  const size_t XSZ = (size_t)Bc * Sc * Dc;       // 16,809,984
  const size_t FFSZ = (size_t)Bc * Sc * FFc;     // >= BS*768

  char* p = (char*)d_ws;
  unsigned short* x = (unsigned short*)p;   p += XSZ * 2;   // bf16 residual
  unsigned short* y = (unsigned short*)p;   p += XSZ * 2;
  unsigned short* ao = (unsigned short*)p;  p += XSZ * 2;
  unsigned short* big = (unsigned short*)p; p += FFSZ * 2;
  unsigned short* qkv = big;                // [BS][768], overlapped with ff
  unsigned short* ff = big;                 // [BS][1024]
  unsigned short* cpw_b = (unsigned short*)p;      // 256x512
  unsigned short* qkvw_b = cpw_b + 131072;          // [L][768][256]
  unsigned short* Wo_b = qkvw_b + 2 * 768 * 256;    // [L][256][256]
  unsigned short* f1_b = Wo_b + 131072;             // [L][1024][256]
  unsigned short* f2_b = f1_b + 524288;             // [L][256][1024]
  float* qkvb = (float*)(f2_b + 524288);            // [L][768]

  const int BS = Bc * Sc;  // 65664 = 513*128
  auto sgrid = [](int MB, int NB) { return (unsigned)(NB * (((MB + 7) >> 3) << 3)); };

  CastTab t;
  t.src[0] = cp_w;  t.dst[0] = cpw_b; t.n4[0] = 131072 / 4;
  t.src[1] = Wo;    t.dst[1] = Wo_b;  t.n4[1] = 131072 / 4;
  t.src[2] = f1w;   t.dst[2] = f1_b;  t.n4[2] = 524288 / 4;
  t.src[3] = f2w;   t.dst[3] = f2_b;  t.n4[3] = 524288 / 4;
  for (int l = 0; l < 2; ++l) {
    t.src[4 + l * 3 + 0] = Wq + l * 65536;
    t.src[4 + l * 3 + 1] = Wk + l * 65536;
    t.src[4 + l * 3 + 2] = Wv + l * 65536;
    t.dst[4 + l * 3 + 0] = qkvw_b + l * 196608 + 0 * 65536;
    t.dst[4 + l * 3 + 1] = qkvw_b + l * 196608 + 1 * 65536;
    t.dst[4 + l * 3 + 2] = qkvw_b + l * 196608 + 2 * 65536;
    t.n4[4 + l * 3 + 0] = 65536 / 4;
    t.n4[4 + l * 3 + 1] = 65536 / 4;
    t.n4[4 + l * 3 + 2] = 65536 / 4;
  }
  cast_multi<<<dim3(128, 10), 256, 0, stream>>>(t);
  bias_concat<<<6, 256, 0, stream>>>(bq, bk, bv, qkvb);

  // Embed: candidates (fp32, fused cast) -> x rows [2,1026); rows 0,1 direct.
  gemm_mfma<1, 1, 1><<<sgrid(512, 2), 256, 0, stream>>>(
      cands, cpw_b, cp_b, type_emb + 2 * Dc, x, Dc, Cc, Dc, 512, 2);
  embed_qd<<<Bc, 256, 0, stream>>>(query, qp_w, qp_b, dustbin, type_emb, x);

  for (int l = 0; l < 2; ++l) {
    ln_kernel<<<(BS + 15) / 16, 256, 0, stream>>>(x, ln1_w + l * Dc, ln1_b + l * Dc, y, BS);
    // Fused QKV: N=768, out pitch 768.
    gemm_mfma<4, 0, 0><<<sgrid(513, 6), 256, 0, stream>>>(
        y, qkvw_b + l * 196608, qkvb + l * 768, nullptr, qkv, 768, Dc, 768, 513, 6);
    attn_fused<<<Bc * Hc + Bc * 8, 256, 0, stream>>>(qkv, mask, ao);
    gemm_mfma<2, 0, 0><<<sgrid(513, 2), 256, 0, stream>>>(
        ao, Wo_b + l * 65536, bo + l * Dc, x, x, Dc, Dc, Dc, 513, 2);
    ln_kernel<<<(BS + 15) / 16, 256, 0, stream>>>(x, ln2_w + l * Dc, ln2_b + l * Dc, y, BS);
    gemm_mfma<3, 0, 0><<<sgrid(513, 8), 256, 0, stream>>>(
        y, f1_b + l * 524288 / 2, f1b + l * FFc, nullptr, ff, FFc, Dc, FFc, 513, 8);
    gemm_mfma<2, 0, 0><<<sgrid(513, 2), 256, 0, stream>>>(
        ff, f2_b + l * 524288 / 2, f2b + l * Dc, x, x, Dc, FFc, Dc, 513, 2);
  }

  head_kernel<<<(Bc * 1025 + 15) / 16, 256, 0, stream>>>(x, hlw, hlb, hw, hb, mask, out);
}